// Round 4
// baseline (106.725 us; speedup 1.0000x reference)
//
#include <hip/hip_runtime.h>
#include <math.h>

// Problem constants (fixed by the reference setup_inputs).
constexpr int B_ = 256;
constexpr int L_ = 16384;
constexpr int C_ = 4;
constexpr int THREADS = 1024;             // 16 waves/block, 1 block per row
constexpr int NVAL = 11;                  // ce, cnt, mat[9]
constexpr int NWAVE = THREADS / 64;       // 16

// Kernel 1: one block per sample row. R4 structure: R0's unconditional body
// (measured best: guards cost 1.3-1.6 us for zero critical-path benefit,
// since duration = slowest block = a full-length row) with ONE delta: all
// 20 loads (4 int4 + 16 float4 = 20 KB/thread-group) are issued up-front
// before any compute, maximizing memory-level parallelism per wave. The
// per-element math and reduction order are bit-identical to R0 (absmax 0).
//
// Session ledger:
//  R0: unconditional, loads interleaved per-iter          -> 104.8 us (best)
//  R1: guarded iters 2-3, labels loaded in-iter           -> 106.0 (guard
//      serialized label-wait -> pred-load; fetch cut masked)
//  R2: + spin-flag fusion of final reduce                 -> 115.5 (NEVER
//      fuse via spin; block-0 poll + serialization cost ~10 us)
//  R3: guarded, labels hoisted                            -> 106.4 (skip is
//      structurally useless: critical path = full row; kernel not BW-bound)
//  => row kernel ~16.4 us vs 12.9 us byte floor: latency/issue-limited.
__global__ __launch_bounds__(THREADS) void dmice_row(
    const float* __restrict__ pred, const int* __restrict__ labels,
    float* __restrict__ rowout) {
  const int b = blockIdx.x;               // 0 .. B_-1
  const float* p0 = pred + (size_t)b * (C_ * L_);
  const float* p1 = p0 + L_;
  const float* p2 = p0 + 2 * L_;
  const float* p3 = p0 + 3 * L_;
  const int* lb = labels + (size_t)b * L_;
  const int t = threadIdx.x;
  const int base = t * 4;                 // iter it covers base + it*4096

  // ---- issue ALL loads up front: 4 label int4 + 16 pred float4 ----
  const int4 l0 = *(const int4*)(lb + base);
  const int4 l1 = *(const int4*)(lb + base + 4096);
  const int4 l2 = *(const int4*)(lb + base + 8192);
  const int4 l3 = *(const int4*)(lb + base + 12288);

  const float4 a0 = *(const float4*)(p0 + base);
  const float4 a1 = *(const float4*)(p1 + base);
  const float4 a2 = *(const float4*)(p2 + base);
  const float4 a3 = *(const float4*)(p3 + base);
  const float4 b0 = *(const float4*)(p0 + base + 4096);
  const float4 b1 = *(const float4*)(p1 + base + 4096);
  const float4 b2 = *(const float4*)(p2 + base + 4096);
  const float4 b3 = *(const float4*)(p3 + base + 4096);
  const float4 c0 = *(const float4*)(p0 + base + 8192);
  const float4 c1 = *(const float4*)(p1 + base + 8192);
  const float4 c2 = *(const float4*)(p2 + base + 8192);
  const float4 c3 = *(const float4*)(p3 + base + 8192);
  const float4 d0 = *(const float4*)(p0 + base + 12288);
  const float4 d1 = *(const float4*)(p1 + base + 12288);
  const float4 d2 = *(const float4*)(p2 + base + 12288);
  const float4 d3 = *(const float4*)(p3 + base + 12288);

  float ce = 0.f, cnt = 0.f;
  float m00 = 0.f, m01 = 0.f, m02 = 0.f;
  float m10 = 0.f, m11 = 0.f, m12 = 0.f;
  float m20 = 0.f, m21 = 0.f, m22 = 0.f;

  // Bit-identical to R0's proc (pad check per element, same op order).
  auto proc = [&](float v0, float v1, float v2, float v3, int lab) {
    float mx = fmaxf(fmaxf(v0, v1), fmaxf(v2, v3));
    float e0 = __expf(v0 - mx);
    float e1 = __expf(v1 - mx);
    float e2 = __expf(v2 - mx);
    float e3 = __expf(v3 - mx);
    float s3 = e0 + e1 + e2;
    float s4 = s3 + e3;
    if (lab != 3) {
      float xl = (lab == 0) ? v0 : ((lab == 1) ? v1 : v2);
      ce += (mx + __logf(s4)) - xl;       // -log_softmax[label]
      cnt += 1.f;
      float inv = 1.f / s3;
      float r0 = (lab == 0) ? inv : 0.f;
      float r1 = (lab == 1) ? inv : 0.f;
      float r2 = (lab == 2) ? inv : 0.f;
      m00 = fmaf(e0, r0, m00); m01 = fmaf(e1, r0, m01); m02 = fmaf(e2, r0, m02);
      m10 = fmaf(e0, r1, m10); m11 = fmaf(e1, r1, m11); m12 = fmaf(e2, r1, m12);
      m20 = fmaf(e0, r2, m20); m21 = fmaf(e1, r2, m21); m22 = fmaf(e2, r2, m22);
    }
  };

  proc(a0.x, a1.x, a2.x, a3.x, l0.x);
  proc(a0.y, a1.y, a2.y, a3.y, l0.y);
  proc(a0.z, a1.z, a2.z, a3.z, l0.z);
  proc(a0.w, a1.w, a2.w, a3.w, l0.w);
  proc(b0.x, b1.x, b2.x, b3.x, l1.x);
  proc(b0.y, b1.y, b2.y, b3.y, l1.y);
  proc(b0.z, b1.z, b2.z, b3.z, l1.z);
  proc(b0.w, b1.w, b2.w, b3.w, l1.w);
  proc(c0.x, c1.x, c2.x, c3.x, l2.x);
  proc(c0.y, c1.y, c2.y, c3.y, l2.y);
  proc(c0.z, c1.z, c2.z, c3.z, l2.z);
  proc(c0.w, c1.w, c2.w, c3.w, l2.w);
  proc(d0.x, d1.x, d2.x, d3.x, l3.x);
  proc(d0.y, d1.y, d2.y, d3.y, l3.y);
  proc(d0.z, d1.z, d2.z, d3.z, l3.z);
  proc(d0.w, d1.w, d2.w, d3.w, l3.w);

  // Reduction: wave64 shuffle, then LDS across 16 waves (identical to R0).
  float vals[NVAL] = {ce, cnt, m00, m01, m02, m10, m11, m12, m20, m21, m22};
#pragma unroll
  for (int off = 32; off > 0; off >>= 1) {
#pragma unroll
    for (int k = 0; k < NVAL; ++k) vals[k] += __shfl_down(vals[k], off, 64);
  }
  __shared__ float red[NWAVE][NVAL];
  const int wave = t >> 6, lane = t & 63;
  if (lane == 0) {
#pragma unroll
    for (int k = 0; k < NVAL; ++k) red[wave][k] = vals[k];
  }
  __syncthreads();
  if (t == 0) {
    float s[NVAL];
#pragma unroll
    for (int k = 0; k < NVAL; ++k) {
      float acc = 0.f;
#pragma unroll
      for (int w = 0; w < NWAVE; ++w) acc += red[w][k];
      s[k] = acc;
    }
    float cs = s[1];
    float inv = 1.f / cs;                 // j[b] = valid count (pads suffix)
    float a00 = s[2] * inv, a01 = s[3] * inv, a02 = s[4] * inv;
    float a10 = s[5] * inv, a11 = s[6] * inv, a12 = s[7] * inv;
    float a20 = s[8] * inv, a21 = s[9] * inv, a22 = s[10] * inv;
    float det = a00 * (a11 * a22 - a12 * a21)
              - a01 * (a10 * a22 - a12 * a20)
              + a02 * (a10 * a21 - a11 * a20);
    float lg = __logf(fabsf(det) + 1e-3f);
    float dmi = (det < 0.f) ? lg : -lg;
    *(float4*)(rowout + (size_t)b * 4) = make_float4(dmi, s[0], cs, 0.f);
  }
}

// Kernel 2: one block, thread b reads row b's {dmi, ce, cnt}, block-reduce,
// write the scalar loss.
__global__ __launch_bounds__(256) void dmice_final(
    const float* __restrict__ rowout, float* __restrict__ out) {
  const int b = threadIdx.x;  // 0..255 == B_
  const float4 v = *(const float4*)(rowout + (size_t)b * 4);
  float r[3] = {v.x, v.y, v.z};
#pragma unroll
  for (int off = 32; off > 0; off >>= 1) {
#pragma unroll
    for (int k = 0; k < 3; ++k) r[k] += __shfl_down(r[k], off, 64);
  }
  __shared__ float red[4][3];
  const int wave = b >> 6, lane = b & 63;
  if (lane == 0) {
#pragma unroll
    for (int k = 0; k < 3; ++k) red[wave][k] = r[k];
  }
  __syncthreads();
  if (b == 0) {
    float dmi_s = red[0][0] + red[1][0] + red[2][0] + red[3][0];
    float ce_s  = red[0][1] + red[1][1] + red[2][1] + red[3][1];
    float cnt_s = red[0][2] + red[1][2] + red[2][2] + red[3][2];
    out[0] = 0.1f * (dmi_s * (1.f / (float)B_)) + ce_s / cnt_s;
  }
}

extern "C" void kernel_launch(void* const* d_in, const int* in_sizes, int n_in,
                              void* d_out, int out_size, void* d_ws, size_t ws_size,
                              hipStream_t stream) {
  const float* pred = (const float*)d_in[0];
  const int* labels = (const int*)d_in[1];
  float* out = (float*)d_out;
  float* rowout = (float*)d_ws;  // B_ * 4 floats = 4 KiB

  dmice_row<<<B_, THREADS, 0, stream>>>(pred, labels, rowout);
  dmice_final<<<1, 256, 0, stream>>>(rowout, out);
}